// Round 6
// baseline (8992.461 us; speedup 1.0000x reference)
//
#include <hip/hip_runtime.h>

#define NB 32
#define NT 512
#define NI 128
#define NH 1024
#define NG 4096
#define NO 128
#define RS 32

typedef _Float16 f16;
typedef _Float16 f16x8 __attribute__((ext_vector_type(8)));
typedef float f32x4 __attribute__((ext_vector_type(4)));
typedef int int4v __attribute__((ext_vector_type(4)));
typedef unsigned long long ull;

#define MFMA16(a, b, c) __builtin_amdgcn_mfma_f32_16x16x32_f16(a, b, c, 0, 0, 0)
#define SENTD 0x7F7F7F7Fu

__device__ __forceinline__ float sigm(float x) { return 1.f / (1.f + __expf(-x)); }
__device__ __forceinline__ float tanh_(float x) {
    float a = fabsf(x);
    float e = __expf(-2.f * a);
    float r = (1.f - e) / (1.f + e);
    return x < 0.f ? -r : r;
}
__device__ __forceinline__ bool ok16(int4v v) {
    return v.x != (int)SENTD && v.y != (int)SENTD && v.z != (int)SENTD && v.w != (int)SENTD;
}
__device__ __forceinline__ unsigned aload32u(const void* p) {
    return __hip_atomic_load((const unsigned*)p, __ATOMIC_RELAXED, __HIP_MEMORY_SCOPE_AGENT);
}
__device__ __forceinline__ void astore32u(void* p, unsigned v) {
    __hip_atomic_store((unsigned*)p, v, __ATOMIC_RELAXED, __HIP_MEMORY_SCOPE_AGENT);
}
__device__ __forceinline__ void astore64(void* p, ull v) {
    __hip_atomic_store((ull*)p, v, __ATOMIC_RELAXED, __HIP_MEMORY_SCOPE_AGENT);
}
__device__ __forceinline__ f16x8 ld8f(const float* s) {
    float4 x0 = *(const float4*)s, x1 = *(const float4*)(s + 4);
    f16x8 v;
    v[0] = (f16)x0.x; v[1] = (f16)x0.y; v[2] = (f16)x0.z; v[3] = (f16)x0.w;
    v[4] = (f16)x1.x; v[5] = (f16)x1.y; v[6] = (f16)x1.z; v[7] = (f16)x1.w;
    return v;
}
// 16B load, L1-bypass (L2-coherent within XCD)
#define LOAD_SC0(dst, addr) \
    asm volatile("global_load_dwordx4 %0, %1, off sc0" : "=v"(dst) : "v"(addr))
// 16B load, L1+L2-bypass (L3-direct, cross-XCD coherent)
#define LOAD_SC01(dst, addr) \
    asm volatile("global_load_dwordx4 %0, %1, off sc0 sc1" : "=v"(dst) : "v"(addr))
#define WAITV0() do { asm volatile("s_waitcnt vmcnt(0)" ::: "memory"); \
                      __builtin_amdgcn_sched_barrier(0); } while (0)

__global__ void convf16(const float* __restrict__ src, f16* __restrict__ dst, int n) {
    int i = blockIdx.x * blockDim.x + threadIdx.x;
    if (i < n) dst[i] = (f16)src[i];
}

// ---------------------------------------------------------------------------
// xp1 precompute: xp1[t][half][s][uu][g][b] (f16) = state[b][t][:]@Wih0[col,:] + b0
// col = g*1024 + s*32 + uu.  Grid (NT, 4); block 256.
// ---------------------------------------------------------------------------
__global__ __launch_bounds__(256) void xp1gemm(
    const float* __restrict__ state, const float* __restrict__ Wih0f,
    const float* __restrict__ b0, f16* __restrict__ xp1)
{
    const int t = blockIdx.x, cb = blockIdx.y;
    const int tid = threadIdx.x;
    const int w = tid >> 6, lane = tid & 63, llo = lane & 15, lhi = lane >> 4;
    const int C0 = cb * 1024 + w * 256;

    f16x8 a[2][4];
#pragma unroll
    for (int Mt = 0; Mt < 2; ++Mt)
#pragma unroll
        for (int kf = 0; kf < 4; ++kf) {
            int b = Mt * 16 + llo, k = kf * 32 + lhi * 8;
            a[Mt][kf] = ld8f(state + ((size_t)b * NT + t) * NI + k);
        }
    f32x4 acc[2][16];
#pragma unroll
    for (int nt = 0; nt < 16; ++nt) {
        float bb = b0[C0 + nt * 16 + llo];
#pragma unroll
        for (int Mt = 0; Mt < 2; ++Mt)
#pragma unroll
            for (int r = 0; r < 4; ++r) acc[Mt][nt][r] = bb;
    }
#pragma unroll
    for (int nt = 0; nt < 16; ++nt) {
        int col = C0 + nt * 16 + llo;
#pragma unroll
        for (int kf = 0; kf < 4; ++kf) {
            f16x8 bf = ld8f(Wih0f + (size_t)col * NI + kf * 32 + lhi * 8);
            acc[0][nt] = MFMA16(a[0][kf], bf, acc[0][nt]);
            acc[1][nt] = MFMA16(a[1][kf], bf, acc[1][nt]);
        }
    }
#pragma unroll
    for (int Mt = 0; Mt < 2; ++Mt)
#pragma unroll
        for (int nt = 0; nt < 16; ++nt) {
            int col = C0 + nt * 16 + llo;
            int g = col >> 10, u = col & 1023, srt = u >> 5, uu = u & 31;
            ull pk = 0;
#pragma unroll
            for (int r = 0; r < 4; ++r) {
                unsigned short hb = __builtin_bit_cast(unsigned short, (f16)acc[Mt][nt][r]);
                pk |= (ull)hb << (16 * r);
            }
            *(ull*)(xp1 + ((((size_t)t * 2 + Mt) * 32 + srt) * 32 + uu) * 64 + g * 16 + lhi * 4) = pk;
        }
}

// ---------------------------------------------------------------------------
// Persistent kernel. 256 WGs x 256 thr, 1 WG/CU (forced by 84KB dyn LDS).
// Roles by bid%8 (= XCD on MI355X):
//   xcd 0/1: L1 recurrence, half=xcd.  xcd 2/3: L2 recurrence, half=xcd-2.
//   xcd 4-7: P (xp2[t] = h1[t]@Wih1, no bias), batch-octet bg=xcd-4.
// Per recurrent CU: 16 batches x 32 h-units (slot s), weights (K=1024,
// 128 interleaved gate-cols) in VGPRs, K split across 4 waves, LDS reduce.
// Publish: plain store (own L2) + agent atomic store (L3). Local read: sc0
// 16B sentinel-spin (timeout -> sc0 sc1). Cross-XCD read: sc0 sc1 sentinel.
// xp2 ring (32 slots f32, sentinel): consumer re-sentinels after use; P
// back-pressured by per-slot progress counters. Deadlock-free dataflow.
// ---------------------------------------------------------------------------
extern "C" __global__ __launch_bounds__(256, 1) void persist(
    const float* __restrict__ Whh0f, const float* __restrict__ Wih1f,
    const float* __restrict__ Whh1f, const float* __restrict__ b1,
    const f16* __restrict__ xp1,     // [NT][2][32][32][4][16] f16 (b0 folded)
    f16* __restrict__ h1all,         // [NT][NB][NH] f16, 0x7F-filled
    f16* __restrict__ h2all,         // [NT][NB][NH] f16, 0x7F-filled
    float* __restrict__ xp2ring,     // [RS][2][32][32][4][16] f32, 0x7F-filled
    unsigned* __restrict__ prog2)    // [2][32], 0-filled
{
    extern __shared__ char smem[];
    float* gbuf = (float*)smem;             // 32 tiles * 272 f32 = 34816 B
    float* xbuf = (float*)(smem + 34816);   // 2048 f32 = 8192 B
    const int bid = blockIdx.x;
    const int xcd = bid & 7;
    const int s = bid >> 3;                 // slot 0..31
    const int tid = threadIdx.x;
    const int w = tid >> 6, lane = tid & 63, llo = lane & 15, lhi = lane >> 4;

    if (xcd < 4) {
        // ================= recurrent roles (L1 / L2) =================
        const bool isL2 = (xcd >= 2);
        const int half = xcd & 1;
        const float* Wf = isL2 ? Whh1f : Whh0f;
        f16* hall = isL2 ? h2all : h1all;

        f16x8 wr[64];
#pragma unroll
        for (int ct = 0; ct < 8; ++ct)
#pragma unroll
            for (int i = 0; i < 8; ++i) {
                int c = ct * 16 + llo, g = c >> 5, uu = c & 31;
                int col = g * NH + s * 32 + uu;
                int k = w * 256 + i * 32 + lhi * 8;
                wr[ct * 8 + i] = ld8f(Wf + (size_t)col * NH + k);
            }
        const int eb = tid & 15, euu = (tid >> 4) * 2;   // elementwise (b, uu-pair)
        float Bv[2][4] = {};
        if (isL2) {
#pragma unroll
            for (int j = 0; j < 2; ++j)
#pragma unroll
                for (int g = 0; g < 4; ++g)
                    Bv[j][g] = b1[g * NH + s * 32 + euu + j];
        }
        float cc[2] = {0.f, 0.f};

        for (int t = 0; t < NT; ++t) {
            // ---- input projection fetch (in flight across spin/MFMA) ----
            f16x8 xv{};
            int4v x8a, x8b;
            const size_t cuoff = (isL2 ? ((size_t)(t & (RS - 1)) * 2 + half)
                                       : ((size_t)t * 2 + half)) * 32 + s;
            if (!isL2) {
                xv = *(const f16x8*)(xp1 + cuoff * 2048 + tid * 8);
            } else {
                const float* rb = xp2ring + cuoff * 2048 + tid * 8;
                LOAD_SC01(x8a, rb);
                LOAD_SC01(x8b, rb + 4);
            }
            // ---- sentinel-spin previous h (own XCD fast path) ----
            int4v val[8];
            if (t > 0) {
                const f16* hs = hall + ((size_t)(t - 1) * NB + half * 16 + llo) * NH
                                + w * 256 + lhi * 8;
                unsigned pend = 0xFFu;
                int rounds = 0;
                while (pend) {
                    if (rounds < 16) {
#pragma unroll
                        for (int i = 0; i < 8; ++i)
                            if (pend & (1u << i)) LOAD_SC0(val[i], hs + i * 32);
                    } else {
#pragma unroll
                        for (int i = 0; i < 8; ++i)
                            if (pend & (1u << i)) LOAD_SC01(val[i], hs + i * 32);
                    }
                    WAITV0();
#pragma unroll
                    for (int i = 0; i < 8; ++i)
                        if ((pend & (1u << i)) && ok16(val[i])) pend &= ~(1u << i);
                    if (pend) {
                        ++rounds;
                        if (rounds > 2) __builtin_amdgcn_s_sleep(1);
                    }
                }
            } else {
#pragma unroll
                for (int i = 0; i < 8; ++i) val[i] = int4v{};
            }
            // ---- MFMA: K-split partials ----
            f32x4 acc[8] = {};
#pragma unroll
            for (int i = 0; i < 8; ++i) {
                f16x8 av = __builtin_bit_cast(f16x8, val[i]);
#pragma unroll
                for (int ct = 0; ct < 8; ++ct)
                    acc[ct] = MFMA16(av, wr[ct * 8 + i], acc[ct]);
            }
            __syncthreads();   // barrier 1: prev-step LDS reads done
#pragma unroll
            for (int ct = 0; ct < 8; ++ct)
#pragma unroll
                for (int r = 0; r < 4; ++r)
                    gbuf[(w * 8 + ct) * 272 + llo * 17 + lhi * 4 + r] = acc[ct][r];
            // ---- stage input projection into xbuf ----
            if (!isL2) {
#pragma unroll
                for (int j = 0; j < 8; ++j) xbuf[tid * 8 + j] = (float)xv[j];
            } else {
                WAITV0();
                const float* rb = xp2ring + cuoff * 2048 + tid * 8;
                bool ok = ok16(x8a) && ok16(x8b);
                while (!ok) {
                    __builtin_amdgcn_s_sleep(1);
                    LOAD_SC01(x8a, rb);
                    LOAD_SC01(x8b, rb + 4);
                    WAITV0();
                    ok = ok16(x8a) && ok16(x8b);
                }
                float4 f0 = __builtin_bit_cast(float4, x8a);
                float4 f1 = __builtin_bit_cast(float4, x8b);
                xbuf[tid * 8 + 0] = f0.x; xbuf[tid * 8 + 1] = f0.y;
                xbuf[tid * 8 + 2] = f0.z; xbuf[tid * 8 + 3] = f0.w;
                xbuf[tid * 8 + 4] = f1.x; xbuf[tid * 8 + 5] = f1.y;
                xbuf[tid * 8 + 6] = f1.z; xbuf[tid * 8 + 7] = f1.w;
                // re-sentinel the consumed ring chunk (WAR-safe: drained by barrier 2)
                ull sv = 0x7F7F7F7F7F7F7F7FULL;
                astore64((void*)(rb + 0), sv); astore64((void*)(rb + 2), sv);
                astore64((void*)(rb + 4), sv); astore64((void*)(rb + 6), sv);
            }
            __syncthreads();   // barrier 2: gbuf/xbuf ready, resets drained
            if (isL2 && tid == 0) astore32u(&prog2[half * 32 + s], (unsigned)(t + 1));
            // ---- reduce + elementwise + publish (2 items/thread) ----
            unsigned pk = 0;
#pragma unroll
            for (int j = 0; j < 2; ++j) {
                int uu = euu + j;
                float gv[4];
#pragma unroll
                for (int g = 0; g < 4; ++g) {
                    int tile = g * 2 + (uu >> 4), cl = uu & 15;
                    float ss = xbuf[(uu * 4 + g) * 16 + eb] + Bv[j][g];
#pragma unroll
                    for (int w2 = 0; w2 < 4; ++w2)
                        ss += gbuf[(w2 * 8 + tile) * 272 + cl * 17 + eb];
                    gv[g] = ss;
                }
                float i_ = sigm(gv[0]), f_ = sigm(gv[1]);
                float g_ = tanh_(gv[2]), o_ = sigm(gv[3]);
                cc[j] = f_ * cc[j] + i_ * g_;
                float h = o_ * tanh_(cc[j]);
                unsigned short hb = __builtin_bit_cast(unsigned short, (f16)h);
                pk |= (unsigned)hb << (16 * j);
            }
            {
                f16* hp = hall + ((size_t)t * NB + half * 16 + eb) * NH + s * 32 + euu;
                *(volatile unsigned*)hp = pk;      // own-L2 (write-through L1)
                astore32u(hp, pk);                 // L3 (cross-XCD readers)
            }
        }
    } else {
        // ========================= P role =========================
        const int bg = xcd - 4;          // batch octet
        const int half = bg >> 1;
        f16x8 wr[64];
#pragma unroll
        for (int ct = 0; ct < 8; ++ct)
#pragma unroll
            for (int i = 0; i < 8; ++i) {
                int c = ct * 16 + llo, g = c >> 5, uu = c & 31;
                int col = g * NH + s * 32 + uu;
                int k = w * 256 + i * 32 + lhi * 8;
                wr[ct * 8 + i] = ld8f(Wih1f + (size_t)col * NH + k);
            }
        const int eb = tid & 7, euu = tid >> 3;   // elementwise (b, uu), 1 item

        for (int t = 0; t < NT; ++t) {
            // WAR back-pressure: ring slot t&31 free once L2 finished t-25
            if (t >= 25 && tid == 0) {
                while (aload32u(&prog2[half * 32 + s]) < (unsigned)(t - 24))
                    __builtin_amdgcn_s_sleep(16);
            }
            // sentinel-spin h1[t] (cross-XCD, L3-direct)
            int4v val[8];
            {
                const f16* hs = h1all + ((size_t)t * NB + bg * 8 + (llo & 7)) * NH
                                + w * 256 + lhi * 8;
                unsigned pend = 0xFFu;
                int rounds = 0;
                while (pend) {
#pragma unroll
                    for (int i = 0; i < 8; ++i)
                        if (pend & (1u << i)) LOAD_SC01(val[i], hs + i * 32);
                    WAITV0();
#pragma unroll
                    for (int i = 0; i < 8; ++i)
                        if ((pend & (1u << i)) && ok16(val[i])) pend &= ~(1u << i);
                    if (pend) {
                        ++rounds;
                        if (rounds > 2) __builtin_amdgcn_s_sleep(1);
                    }
                }
            }
            f32x4 acc[8] = {};
#pragma unroll
            for (int i = 0; i < 8; ++i) {
                f16x8 av = __builtin_bit_cast(f16x8, val[i]);
#pragma unroll
                for (int ct = 0; ct < 8; ++ct)
                    acc[ct] = MFMA16(av, wr[ct * 8 + i], acc[ct]);
            }
            __syncthreads();
#pragma unroll
            for (int ct = 0; ct < 8; ++ct)
#pragma unroll
                for (int r = 0; r < 4; ++r)
                    gbuf[(w * 8 + ct) * 272 + llo * 17 + lhi * 4 + r] = acc[ct][r];
            __syncthreads();
            {
                float* ro = xp2ring + (((size_t)(t & (RS - 1)) * 2 + half) * 32 + s) * 2048
                            + (euu * 4) * 16 + (bg & 1) * 8 + eb;
#pragma unroll
                for (int g = 0; g < 4; ++g) {
                    int tile = g * 2 + (euu >> 4), cl = euu & 15;
                    float ss = 0.f;
#pragma unroll
                    for (int w2 = 0; w2 < 4; ++w2)
                        ss += gbuf[(w2 * 8 + tile) * 272 + cl * 17 + eb];
                    astore32u(ro + g * 16, __builtin_bit_cast(unsigned, ss));
                }
            }
        }
    }
}

// ---------------------------------------------------------------------------
// Head: out[b][t][o] = h2[b][t][:] @ W_out^T + b_out ; one WG per t
// ---------------------------------------------------------------------------
__device__ __forceinline__ void stage_h(const f16* __restrict__ hsrc, char* smem, int tid) {
    const float4* src = (const float4*)hsrc;
#pragma unroll
    for (int i = 0; i < 16; ++i) {
        int c = i * 256 + tid;
        int off = c * 16;
        int swz = off ^ (((off >> 11) & 7) << 4);
        *(float4*)(smem + swz) = src[c];
    }
}
__device__ __forceinline__ f16x8 afrag(const char* smem, int row, int kk) {
    int off = (row << 11) + kk * 2;
    off ^= ((row & 7) << 4);
    return *(const f16x8*)(smem + off);
}

__global__ __launch_bounds__(256) void head_kernel(
    const f16* __restrict__ h2all, const f16* __restrict__ Wout,
    const float* __restrict__ bout, float* __restrict__ out)
{
    __shared__ __align__(16) char smem[65536];
    int t = blockIdx.x;
    int tid = threadIdx.x;
    int wave = tid >> 6, lane = tid & 63, lhi = lane >> 4, llo = lane & 15;
    stage_h(h2all + (size_t)t * NB * NH, smem, tid);
    __syncthreads();

    f32x4 acc[2][2];
#pragma unroll
    for (int nt = 0; nt < 2; ++nt) {
        int col = wave * 32 + nt * 16 + llo;
        float bb = bout[col];
#pragma unroll
        for (int r = 0; r < 4; ++r) { acc[0][nt][r] = bb; acc[1][nt][r] = bb; }
    }
#pragma unroll 8
    for (int kt = 0; kt < 32; ++kt) {
        int kk = kt * 32 + lhi * 8;
        f16x8 a0 = afrag(smem, llo, kk);
        f16x8 a1 = afrag(smem, 16 + llo, kk);
#pragma unroll
        for (int nt = 0; nt < 2; ++nt) {
            int col = wave * 32 + nt * 16 + llo;
            f16x8 bf = *(const f16x8*)(Wout + (size_t)col * NH + kk);
            acc[0][nt] = MFMA16(a0, bf, acc[0][nt]);
            acc[1][nt] = MFMA16(a1, bf, acc[1][nt]);
        }
    }
#pragma unroll
    for (int nt = 0; nt < 2; ++nt) {
        int col = wave * 32 + nt * 16 + llo;
#pragma unroll
        for (int r = 0; r < 4; ++r) {
            out[(size_t)(lhi * 4 + r) * NT * NO + (size_t)t * NO + col] = acc[0][nt][r];
            out[(size_t)(16 + lhi * 4 + r) * NT * NO + (size_t)t * NO + col] = acc[1][nt][r];
        }
    }
}

extern "C" void kernel_launch(void* const* d_in, const int* in_sizes, int n_in,
                              void* d_out, int out_size, void* d_ws, size_t ws_size,
                              hipStream_t stream)
{
    const float* state = (const float*)d_in[0];
    const float* Wih0f = (const float*)d_in[1];
    const float* Whh0f = (const float*)d_in[2];
    const float* b0    = (const float*)d_in[3];
    const float* Wih1f = (const float*)d_in[4];
    const float* Whh1f = (const float*)d_in[5];
    const float* b1    = (const float*)d_in[6];
    const float* Woutf = (const float*)d_in[7];
    const float* bout  = (const float*)d_in[8];
    float* out = (float*)d_out;
    (void)in_sizes; (void)n_in; (void)out_size; (void)ws_size;

    size_t off = 0;
    char* base = (char*)d_ws;
    auto alloc = [&](size_t bytes) -> void* {
        void* p = base + off;
        off += (bytes + 255) & ~(size_t)255;
        return p;
    };
    f16*      Wout    = (f16*)alloc((size_t)NO * NH * 2);
    f16*      xp1     = (f16*)alloc((size_t)NT * NB * NG * 2);        // 134 MB
    f16*      h1all   = (f16*)alloc((size_t)NT * NB * NH * 2);        // 32 MB
    f16*      h2all   = (f16*)alloc((size_t)NT * NB * NH * 2);        // 32 MB
    float*    xp2ring = (float*)alloc((size_t)RS * NB * NG * 4);      // 16 MB
    unsigned* prog2   = (unsigned*)alloc(2 * 32 * 4);

    convf16<<<(NO * NH + 255) / 256, 256, 0, stream>>>(Woutf, Wout, NO * NH);
    // sentinel-fill h1all + h2all + xp2ring (contiguous allocations)
    hipMemsetAsync(h1all, 0x7F,
                   (size_t)NT * NB * NH * 2 * 2 + (size_t)RS * NB * NG * 4, stream);
    hipMemsetAsync(prog2, 0, 2 * 32 * 4, stream);

    xp1gemm<<<dim3(NT, 4), 256, 0, stream>>>(state, Wih0f, b0, xp1);

    hipFuncSetAttribute((const void*)persist,
                        hipFuncAttributeMaxDynamicSharedMemorySize, 86016);
    persist<<<256, 256, 86016, stream>>>(Whh0f, Wih1f, Whh1f, b1,
                                         xp1, h1all, h2all, xp2ring, prog2);
    head_kernel<<<NT, 256, 0, stream>>>(h2all, Wout, bout, out);
}

// Round 8
// 2986.429 us; speedup vs baseline: 3.0111x; 3.0111x over previous
//
#include <hip/hip_runtime.h>

#define NB 32
#define NT 512
#define NI 128
#define NH 1024
#define NG 4096
#define NO 128

typedef _Float16 f16;
typedef _Float16 f16x8 __attribute__((ext_vector_type(8)));
typedef float f32x4 __attribute__((ext_vector_type(4)));
typedef int int4v __attribute__((ext_vector_type(4)));
typedef unsigned long long ull;

#define MFMA16(a, b, c) __builtin_amdgcn_mfma_f32_16x16x32_f16(a, b, c, 0, 0, 0)
#define SENTD 0x7F7F7F7Fu

__device__ __forceinline__ float sigm(float x) { return 1.f / (1.f + __expf(-x)); }
__device__ __forceinline__ float tanh_(float x) {
    float a = fabsf(x);
    float e = __expf(-2.f * a);
    float r = (1.f - e) / (1.f + e);
    return x < 0.f ? -r : r;
}
// valid when NO dword equals the 0x7F7F7F7F sentinel (f16 NaN pair; |h|<1
// so real packed h never encodes as it)
__device__ __forceinline__ bool ok16(int4v v) {
    return v.x != (int)SENTD && v.y != (int)SENTD && v.z != (int)SENTD && v.w != (int)SENTD;
}
__device__ __forceinline__ void astore64(void* p, ull v) {
    __hip_atomic_store((ull*)p, v, __ATOMIC_RELAXED, __HIP_MEMORY_SCOPE_AGENT);
}
__device__ __forceinline__ f16x8 ld8f(const float* s) {
    float4 x0 = *(const float4*)s, x1 = *(const float4*)(s + 4);
    f16x8 v;
    v[0] = (f16)x0.x; v[1] = (f16)x0.y; v[2] = (f16)x0.z; v[3] = (f16)x0.w;
    v[4] = (f16)x1.x; v[5] = (f16)x1.y; v[6] = (f16)x1.z; v[7] = (f16)x1.w;
    return v;
}
// 16B load, L1+L2-bypass (L3-direct): always coherent with agent-atomic
// stores from any XCD; no fences, no stale-line hazard.
#define LOAD_SC01(dst, addr) \
    asm volatile("global_load_dwordx4 %0, %1, off sc0 sc1" : "=v"(dst) : "v"(addr))
#define WAITV0() do { asm volatile("s_waitcnt vmcnt(0)" ::: "memory"); \
                      __builtin_amdgcn_sched_barrier(0); } while (0)

__global__ void convf16(const float* __restrict__ src, f16* __restrict__ dst, int n) {
    int i = blockIdx.x * blockDim.x + threadIdx.x;
    if (i < n) dst[i] = (f16)src[i];
}

// ---------------------------------------------------------------------------
// Persistent pipeline (R4 structure, proven correct): 256 WGs x 256 thr,
// 1 WG/CU (forced by 84KB dyn LDS).
//  bid [0,128)   R1: layer-1 step, (16 batch, 16 units)/CU, K=1152 (state|h1).
//  bid [128,256) R2: layer-2 step + input proj, (16 batch, 16 units)/CU,
//                two K=1024 matmuls (h1[t]@Wih1 + h2[t-1]@Whh1).
// Weights in VGPRs (K split across 4 waves, 4 gates). A-fragments go straight
// from global loads into MFMA. Producers publish packed 8B agent-scope
// atomic stores (L3-resident). Consumers bulk-read h with SC01 16B loads
// (L3-direct, always fresh); any fragment still sentinel is re-read with the
// same SC01 loads. No flags, no fences, no rings -> deadlock-impossible.
// LDS holds only the padded K-reduction buffer.
// ---------------------------------------------------------------------------
extern "C" __global__ __launch_bounds__(256, 1) void persist(
    const float* __restrict__ Wih0f, const float* __restrict__ Whh0f, const float* __restrict__ b0,
    const float* __restrict__ Wih1f, const float* __restrict__ Whh1f, const float* __restrict__ b1,
    const f16* __restrict__ state16,
    f16* __restrict__ h1all,      // [NT][NB][NH], 0x7F-filled
    f16* __restrict__ h2all)      // [NT][NB][NH], 0x7F-filled
{
    extern __shared__ char smem[];
    float* gbuf = (float*)smem;   // [16][16*17] f32 partials, +17 pad
    const int bid = blockIdx.x;
    const int tid = threadIdx.x;
    const int w = tid >> 6;
    const int lane = tid & 63;
    const int llo = lane & 15;
    const int lhi = lane >> 4;
    const int rb = tid >> 2;        // elementwise: batch row (threads 0..63)
    const int uq = (tid & 3) * 4;   // elementwise: unit quad base

    if (bid < 128) {
        // ============================ R1 ============================
        const int bs = bid >> 6, us = bid & 63;
        const int bbase = bs * 16, ubase = us * 16;
        // weights: wave w owns ks = w*9+i (K=1152), 4 gate-column blocks
        f16x8 wr[36];
#pragma unroll
        for (int g = 0; g < 4; ++g)
#pragma unroll
            for (int i = 0; i < 9; ++i) {
                int kpos = (w * 9 + i) * 32 + lhi * 8;
                int col = g * NH + ubase + llo;
                const float* s = (kpos < 128) ? (Wih0f + (size_t)col * NI + kpos)
                                              : (Whh0f + (size_t)col * NH + (kpos - 128));
                wr[g * 9 + i] = ld8f(s);
            }
        float cc[4] = {0.f, 0.f, 0.f, 0.f};
        float Bi[4], Bff[4], Bg[4], Bo[4];
        if (tid < 64) {
#pragma unroll
            for (int u = 0; u < 4; ++u) {
                Bi[u]  = b0[0 * NH + ubase + uq + u];
                Bff[u] = b0[1 * NH + ubase + uq + u];
                Bg[u]  = b0[2 * NH + ubase + uq + u];
                Bo[u]  = b0[3 * NH + ubase + uq + u];
            }
        }

        for (int t = 0; t < NT; ++t) {
            const f16* hprev = h1all + (size_t)(t - 1) * NB * NH;
            const int row = bbase + llo;
            // ---- bulk SC01 loads (L3-direct), sentinel-validate, SC01 retry ----
            int4v vv[9];
#pragma unroll
            for (int i = 0; i < 9; ++i) {
                int kpos = (w * 9 + i) * 32 + lhi * 8;
                if (kpos < 128)
                    vv[i] = *(const int4v*)(state16 + ((size_t)row * NT + t) * NI + kpos);
                else if (t > 0) {
                    LOAD_SC01(vv[i], hprev + (size_t)row * NH + (kpos - 128));
                } else
                    vv[i] = int4v{};
            }
            if (t > 0) {
                WAITV0();
                unsigned pend = 0;
#pragma unroll
                for (int i = 0; i < 9; ++i) {
                    int kpos = (w * 9 + i) * 32 + lhi * 8;
                    if (kpos >= 128 && !ok16(vv[i])) pend |= 1u << i;
                }
                while (__builtin_expect(pend != 0, 0)) {
#pragma unroll
                    for (int i = 0; i < 9; ++i)
                        if (pend & (1u << i)) {
                            int kpos = (w * 9 + i) * 32 + lhi * 8;
                            LOAD_SC01(vv[i], hprev + (size_t)row * NH + (kpos - 128));
                        }
                    WAITV0();
#pragma unroll
                    for (int i = 0; i < 9; ++i)
                        if ((pend & (1u << i)) && ok16(vv[i])) pend &= ~(1u << i);
                    if (pend) __builtin_amdgcn_s_sleep(1);
                }
            }
            // ---- MFMA directly on loaded fragments (K-split partials) ----
            f32x4 acc[4] = {};
#pragma unroll
            for (int i = 0; i < 9; ++i) {
                f16x8 av = __builtin_bit_cast(f16x8, vv[i]);
#pragma unroll
                for (int g = 0; g < 4; ++g)
                    acc[g] = MFMA16(av, wr[g * 9 + i], acc[g]);
            }
            __syncthreads();   // gbuf free (prev step's reads done)
#pragma unroll
            for (int g = 0; g < 4; ++g)
#pragma unroll
                for (int r = 0; r < 4; ++r)
                    gbuf[(w * 4 + g) * 272 + (lhi * 4 + r) * 17 + llo] = acc[g][r];
            __syncthreads();
            // ---- reduce + elementwise + packed publish (threads 0..63) ----
            if (tid < 64) {
                ull pack = 0;
#pragma unroll
                for (int u = 0; u < 4; ++u) {
                    int un = uq + u;
                    float s0 = 0, s1 = 0, s2 = 0, s3 = 0;
#pragma unroll
                    for (int w2 = 0; w2 < 4; ++w2) {
                        s0 += gbuf[(w2 * 4 + 0) * 272 + rb * 17 + un];
                        s1 += gbuf[(w2 * 4 + 1) * 272 + rb * 17 + un];
                        s2 += gbuf[(w2 * 4 + 2) * 272 + rb * 17 + un];
                        s3 += gbuf[(w2 * 4 + 3) * 272 + rb * 17 + un];
                    }
                    float i_ = sigm(s0 + Bi[u]), f_ = sigm(s1 + Bff[u]);
                    float g_ = tanh_(s2 + Bg[u]), o_ = sigm(s3 + Bo[u]);
                    cc[u] = f_ * cc[u] + i_ * g_;
                    float h = o_ * tanh_(cc[u]);
                    unsigned short hb = __builtin_bit_cast(unsigned short, (f16)h);
                    pack |= (ull)hb << (16 * u);
                }
                astore64(h1all + ((size_t)t * NB + bbase + rb) * NH + ubase + uq, pack);
            }
        }
    } else {
        // ====================== R2 (merged P) ======================
        const int b2 = bid - 128, bs = b2 >> 6, us = b2 & 63;
        const int bbase = bs * 16, ubase = us * 16;
        f16x8 wr1[32], wr2[32];   // Wih1, Whh1: wave w owns ks = w*8+i
#pragma unroll
        for (int g = 0; g < 4; ++g)
#pragma unroll
            for (int i = 0; i < 8; ++i) {
                int kpos = (w * 8 + i) * 32 + lhi * 8;
                int col = g * NH + ubase + llo;
                wr1[g * 8 + i] = ld8f(Wih1f + (size_t)col * NH + kpos);
                wr2[g * 8 + i] = ld8f(Whh1f + (size_t)col * NH + kpos);
            }
        float cc[4] = {0.f, 0.f, 0.f, 0.f};
        float Bi[4], Bff[4], Bg[4], Bo[4];
        if (tid < 64) {
#pragma unroll
            for (int u = 0; u < 4; ++u) {
                Bi[u]  = b1[0 * NH + ubase + uq + u];
                Bff[u] = b1[1 * NH + ubase + uq + u];
                Bg[u]  = b1[2 * NH + ubase + uq + u];
                Bo[u]  = b1[3 * NH + ubase + uq + u];
            }
        }
        const int row = bbase + llo;

        for (int t = 0; t < NT; ++t) {
            const f16* A1 = h1all + (size_t)t * NB * NH;
            const f16* A2 = h2all + (size_t)(t - 1) * NB * NH;
            int4v v1[8], v2[8];
#pragma unroll
            for (int i = 0; i < 8; ++i) {
                int kpos = (w * 8 + i) * 32 + lhi * 8;
                LOAD_SC01(v1[i], A1 + (size_t)row * NH + kpos);
            }
            if (t > 0) {
#pragma unroll
                for (int i = 0; i < 8; ++i) {
                    int kpos = (w * 8 + i) * 32 + lhi * 8;
                    LOAD_SC01(v2[i], A2 + (size_t)row * NH + kpos);
                }
            } else {
#pragma unroll
                for (int i = 0; i < 8; ++i) v2[i] = int4v{};
            }
            WAITV0();
            unsigned p1 = 0, p2 = 0;
#pragma unroll
            for (int i = 0; i < 8; ++i) {
                if (!ok16(v1[i])) p1 |= 1u << i;
                if (t > 0 && !ok16(v2[i])) p2 |= 1u << i;
            }
            while (__builtin_expect((p1 | p2) != 0, 0)) {
#pragma unroll
                for (int i = 0; i < 8; ++i) {
                    int kpos = (w * 8 + i) * 32 + lhi * 8;
                    if (p1 & (1u << i)) LOAD_SC01(v1[i], A1 + (size_t)row * NH + kpos);
                    if (p2 & (1u << i)) LOAD_SC01(v2[i], A2 + (size_t)row * NH + kpos);
                }
                WAITV0();
#pragma unroll
                for (int i = 0; i < 8; ++i) {
                    if ((p1 & (1u << i)) && ok16(v1[i])) p1 &= ~(1u << i);
                    if ((p2 & (1u << i)) && ok16(v2[i])) p2 &= ~(1u << i);
                }
                if (p1 | p2) __builtin_amdgcn_s_sleep(1);
            }

            f32x4 acc[4] = {};
#pragma unroll
            for (int i = 0; i < 8; ++i) {
                f16x8 a1 = __builtin_bit_cast(f16x8, v1[i]);
                f16x8 a2 = __builtin_bit_cast(f16x8, v2[i]);
#pragma unroll
                for (int g = 0; g < 4; ++g) {
                    acc[g] = MFMA16(a1, wr1[g * 8 + i], acc[g]);
                    acc[g] = MFMA16(a2, wr2[g * 8 + i], acc[g]);
                }
            }
            __syncthreads();
#pragma unroll
            for (int g = 0; g < 4; ++g)
#pragma unroll
                for (int r = 0; r < 4; ++r)
                    gbuf[(w * 4 + g) * 272 + (lhi * 4 + r) * 17 + llo] = acc[g][r];
            __syncthreads();
            if (tid < 64) {
                ull pack = 0;
#pragma unroll
                for (int u = 0; u < 4; ++u) {
                    int un = uq + u;
                    float s0 = 0, s1 = 0, s2 = 0, s3 = 0;
#pragma unroll
                    for (int w2 = 0; w2 < 4; ++w2) {
                        s0 += gbuf[(w2 * 4 + 0) * 272 + rb * 17 + un];
                        s1 += gbuf[(w2 * 4 + 1) * 272 + rb * 17 + un];
                        s2 += gbuf[(w2 * 4 + 2) * 272 + rb * 17 + un];
                        s3 += gbuf[(w2 * 4 + 3) * 272 + rb * 17 + un];
                    }
                    float i_ = sigm(s0 + Bi[u]), f_ = sigm(s1 + Bff[u]);
                    float g_ = tanh_(s2 + Bg[u]), o_ = sigm(s3 + Bo[u]);
                    cc[u] = f_ * cc[u] + i_ * g_;
                    float h = o_ * tanh_(cc[u]);
                    unsigned short hb = __builtin_bit_cast(unsigned short, (f16)h);
                    pack |= (ull)hb << (16 * u);
                }
                astore64(h2all + ((size_t)t * NB + bbase + rb) * NH + ubase + uq, pack);
            }
        }
    }
}

// ---------------------------------------------------------------------------
// Head: out[b][t][o] = h2[b][t][:] @ W_out^T + b_out ; one WG per t
// ---------------------------------------------------------------------------
__device__ __forceinline__ void stage_h(const f16* __restrict__ hsrc, char* smem, int tid) {
    const float4* src = (const float4*)hsrc;
#pragma unroll
    for (int i = 0; i < 16; ++i) {
        int c = i * 256 + tid;
        int off = c * 16;
        int swz = off ^ (((off >> 11) & 7) << 4);
        *(float4*)(smem + swz) = src[c];
    }
}
__device__ __forceinline__ f16x8 afrag(const char* smem, int row, int kk) {
    int off = (row << 11) + kk * 2;
    off ^= ((row & 7) << 4);
    return *(const f16x8*)(smem + off);
}

__global__ __launch_bounds__(256) void head_kernel(
    const f16* __restrict__ h2all, const f16* __restrict__ Wout,
    const float* __restrict__ bout, float* __restrict__ out)
{
    __shared__ __align__(16) char smem[65536];
    int t = blockIdx.x;
    int tid = threadIdx.x;
    int wave = tid >> 6, lane = tid & 63, lhi = lane >> 4, llo = lane & 15;
    stage_h(h2all + (size_t)t * NB * NH, smem, tid);
    __syncthreads();

    f32x4 acc[2][2];
#pragma unroll
    for (int nt = 0; nt < 2; ++nt) {
        int col = wave * 32 + nt * 16 + llo;
        float bb = bout[col];
#pragma unroll
        for (int r = 0; r < 4; ++r) { acc[0][nt][r] = bb; acc[1][nt][r] = bb; }
    }
#pragma unroll 8
    for (int kt = 0; kt < 32; ++kt) {
        int kk = kt * 32 + lhi * 8;
        f16x8 a0 = afrag(smem, llo, kk);
        f16x8 a1 = afrag(smem, 16 + llo, kk);
#pragma unroll
        for (int nt = 0; nt < 2; ++nt) {
            int col = wave * 32 + nt * 16 + llo;
            f16x8 bf = *(const f16x8*)(Wout + (size_t)col * NH + kk);
            acc[0][nt] = MFMA16(a0, bf, acc[0][nt]);
            acc[1][nt] = MFMA16(a1, bf, acc[1][nt]);
        }
    }
#pragma unroll
    for (int nt = 0; nt < 2; ++nt) {
        int col = wave * 32 + nt * 16 + llo;
#pragma unroll
        for (int r = 0; r < 4; ++r) {
            out[(size_t)(lhi * 4 + r) * NT * NO + (size_t)t * NO + col] = acc[0][nt][r];
            out[(size_t)(16 + lhi * 4 + r) * NT * NO + (size_t)t * NO + col] = acc[1][nt][r];
        }
    }
}

extern "C" void kernel_launch(void* const* d_in, const int* in_sizes, int n_in,
                              void* d_out, int out_size, void* d_ws, size_t ws_size,
                              hipStream_t stream)
{
    const float* state = (const float*)d_in[0];
    const float* Wih0f = (const float*)d_in[1];
    const float* Whh0f = (const float*)d_in[2];
    const float* b0    = (const float*)d_in[3];
    const float* Wih1f = (const float*)d_in[4];
    const float* Whh1f = (const float*)d_in[5];
    const float* b1    = (const float*)d_in[6];
    const float* Woutf = (const float*)d_in[7];
    const float* bout  = (const float*)d_in[8];
    float* out = (float*)d_out;
    (void)in_sizes; (void)n_in; (void)out_size; (void)ws_size;

    size_t off = 0;
    char* base = (char*)d_ws;
    auto alloc = [&](size_t bytes) -> void* {
        void* p = base + off;
        off += (bytes + 255) & ~(size_t)255;
        return p;
    };
    f16* state16 = (f16*)alloc((size_t)NB * NT * NI * 2);
    f16* Wout    = (f16*)alloc((size_t)NO * NH * 2);
    f16* h1all   = (f16*)alloc((size_t)NT * NB * NH * 2);
    f16* h2all   = (f16*)alloc((size_t)NT * NB * NH * 2);

    convf16<<<(NB * NT * NI + 255) / 256, 256, 0, stream>>>(state, state16, NB * NT * NI);
    convf16<<<(NO * NH + 255) / 256, 256, 0, stream>>>(Woutf, Wout, NO * NH);
    // sentinel-fill h1all+h2all (contiguous) — memset's dirty lines are
    // flushed at its own kernel end; consumers bypass L2 anyway (SC01)
    hipMemsetAsync(h1all, 0x7F, (size_t)2 * NT * NB * NH * 2, stream);

    hipFuncSetAttribute((const void*)persist,
                        hipFuncAttributeMaxDynamicSharedMemorySize, 86016);
    persist<<<256, 256, 86016, stream>>>(Wih0f, Whh0f, b0, Wih1f, Whh1f, b1,
                                         state16, h1all, h2all);
    head_kernel<<<NT, 256, 0, stream>>>(h2all, Wout, bout, out);
}